// Round 5
// baseline (560.699 us; speedup 1.0000x reference)
//
#include <hip/hip_runtime.h>
#include <hip/hip_bf16.h>

// ---------------------------------------------------------------------------
// InterpretableMultiHeadAttention  (B=8, S=1024, D=1024, H=16, dk=64)
//   outputs [B,S,D] fp32 ; attn [B,Sq,H,Sk] fp32  (concatenated in d_out)
// Pipeline:
//   1) proj_qk : qs = (q @ Wq^T)/8, ks = k @ Wk^T   (bf16, [b,s,(h,e)] layout)
//   2) proj_v  : vsT = (v @ Wv^T)^T                 (bf16, [b][e][t] layout)
//   3) attn    : SINGLE-pass QK^T (swapped operands -> P^T fragments), exp
//                kept register-resident as 128 packed-bf16 VGPRs per lane;
//                l accumulated in f32; post-loop: NT-store attn = e*inv,
//                LDS roundtrip e -> PV A-frag, PV MFMA (unnormalized, scaled
//                at end).  NOTE: QK output has query=COL (lane r) but PV
//                output has query=ROW (4g+j) -> heads must be scaled by
//                invq[j] = __shfl(inv, 4g+j), NOT the lane's own inv.
//   4) out     : outputs = mean_h(heads) @ Wo^T     (VALU)
// All f32->bf16 conversions are round-to-nearest-even.
// ---------------------------------------------------------------------------

typedef __attribute__((ext_vector_type(4))) float f32x4;
typedef __attribute__((ext_vector_type(8))) short bf16x8;
typedef __attribute__((ext_vector_type(2))) unsigned int uint2v;

#define MFMA16(a, b, c) __builtin_amdgcn_mfma_f32_16x16x32_bf16((a), (b), (c), 0, 0, 0)

__device__ __forceinline__ unsigned int rne16(float f) {
  unsigned int u = __float_as_uint(f);
  return u + 0x7fffu + ((u >> 16) & 1u);   // round-to-nearest-even in bit 16
}
__device__ __forceinline__ unsigned int pack2bf(float a, float b) {
  return (rne16(a) >> 16) | (rne16(b) & 0xffff0000u);
}
__device__ __forceinline__ short f2bf(float f) {
  return (short)(rne16(f) >> 16);
}
__device__ __forceinline__ float bf2f(short s) {
  return __uint_as_float(((unsigned int)(unsigned short)s) << 16);
}
__device__ __forceinline__ float bflo(unsigned int u) {
  return __uint_as_float(u << 16);
}
__device__ __forceinline__ float bfhi(unsigned int u) {
  return __uint_as_float(u & 0xffff0000u);
}

// ---------------------------------------------------------------------------
// Kernel 1: fused Q/K projection.  A [8192,1024] f32, W [1024,1024] f32 (B^T
// layout, i.e. [out,in]), C [8192,1024] bf16.  grid = (64, 16): y<8 -> Q, else K.
// ---------------------------------------------------------------------------
__global__ __launch_bounds__(256) void proj_qk_kernel(
    const float* __restrict__ qin, const float* __restrict__ kin,
    const float* __restrict__ Wq, const float* __restrict__ Wk,
    __hip_bfloat16* __restrict__ qs, __hip_bfloat16* __restrict__ ks)
{
  const int K = 1024, N = 1024;
  __shared__ short a_lds[128][40];   // padded stride 40 (80B) -> ~2-way banks
  __shared__ short b_lds[128][40];
  const int tid  = threadIdx.x;
  const int lane = tid & 63, wid = tid >> 6;
  const int g = lane >> 4, r = lane & 15;
  const bool isK = blockIdx.y >= 8;
  const float* A = isK ? kin : qin;
  const float* W = isK ? Wk : Wq;
  __hip_bfloat16* C = isK ? ks : qs;
  const float scale = isK ? 1.0f : 0.125f;   // 1/sqrt(dk)=1/8 folded into qs
  const int m0 = blockIdx.x * 128;
  const int n0 = (blockIdx.y & 7) * 128;
  const int wm = (wid >> 1) * 64, wn = (wid & 1) * 64;
  const int lrow = tid >> 3, lcol = (tid & 7) * 4;

  f32x4 acc[4][4];
#pragma unroll
  for (int i = 0; i < 4; ++i)
#pragma unroll
    for (int j = 0; j < 4; ++j) acc[i][j] = (f32x4){0.f, 0.f, 0.f, 0.f};

  for (int k0 = 0; k0 < K; k0 += 32) {
    float4 av[4], wv[4];
#pragma unroll
    for (int p = 0; p < 4; ++p) {
      av[p] = *(const float4*)&A[(m0 + lrow + p * 32) * K + k0 + lcol];
      wv[p] = *(const float4*)&W[(n0 + lrow + p * 32) * K + k0 + lcol];
    }
    __syncthreads();
#pragma unroll
    for (int p = 0; p < 4; ++p) {
      uint2v ua = {pack2bf(av[p].x, av[p].y), pack2bf(av[p].z, av[p].w)};
      uint2v uw = {pack2bf(wv[p].x, wv[p].y), pack2bf(wv[p].z, wv[p].w)};
      *(uint2v*)&a_lds[lrow + p * 32][lcol] = ua;
      *(uint2v*)&b_lds[lrow + p * 32][lcol] = uw;
    }
    __syncthreads();
    bf16x8 af[4], bf[4];
#pragma unroll
    for (int t = 0; t < 4; ++t) {
      af[t] = *(bf16x8*)&a_lds[wm + t * 16 + r][g * 8];
      bf[t] = *(bf16x8*)&b_lds[wn + t * 16 + r][g * 8];
    }
#pragma unroll
    for (int mt = 0; mt < 4; ++mt)
#pragma unroll
      for (int nt = 0; nt < 4; ++nt)
        acc[mt][nt] = MFMA16(af[mt], bf[nt], acc[mt][nt]);
  }

#pragma unroll
  for (int mt = 0; mt < 4; ++mt)
#pragma unroll
    for (int nt = 0; nt < 4; ++nt) {
      const int n = n0 + wn + nt * 16 + r;
#pragma unroll
      for (int j = 0; j < 4; ++j) {
        const int m = m0 + wm + mt * 16 + 4 * g + j;
        C[m * N + n] = __float2bfloat16(acc[mt][nt][j] * scale);
      }
    }
}

// ---------------------------------------------------------------------------
// Kernel 2: V projection, output TRANSPOSED per batch: vsT[b][e][t] bf16.
// M=8192 (b,t), N=64, K=1024.  grid = 64.
// ---------------------------------------------------------------------------
__global__ __launch_bounds__(256) void proj_v_kernel(
    const float* __restrict__ vin, const float* __restrict__ Wv,
    __hip_bfloat16* __restrict__ vsT)
{
  const int K = 1024;
  __shared__ short a_lds[128][40];
  __shared__ short b_lds[64][40];
  const int tid  = threadIdx.x;
  const int lane = tid & 63, wid = tid >> 6;
  const int g = lane >> 4, r = lane & 15;
  const int m0 = blockIdx.x * 128;
  const int wm = wid * 32;
  const int lrow = tid >> 3, lcol = (tid & 7) * 4;

  f32x4 acc[2][4];
#pragma unroll
  for (int i = 0; i < 2; ++i)
#pragma unroll
    for (int j = 0; j < 4; ++j) acc[i][j] = (f32x4){0.f, 0.f, 0.f, 0.f};

  for (int k0 = 0; k0 < K; k0 += 32) {
    float4 av[4], wv2[2];
#pragma unroll
    for (int p = 0; p < 4; ++p)
      av[p] = *(const float4*)&vin[(m0 + lrow + p * 32) * K + k0 + lcol];
#pragma unroll
    for (int p = 0; p < 2; ++p)
      wv2[p] = *(const float4*)&Wv[(lrow + p * 32) * K + k0 + lcol];
    __syncthreads();
#pragma unroll
    for (int p = 0; p < 4; ++p) {
      uint2v ua = {pack2bf(av[p].x, av[p].y), pack2bf(av[p].z, av[p].w)};
      *(uint2v*)&a_lds[lrow + p * 32][lcol] = ua;
    }
#pragma unroll
    for (int p = 0; p < 2; ++p) {
      uint2v uw = {pack2bf(wv2[p].x, wv2[p].y), pack2bf(wv2[p].z, wv2[p].w)};
      *(uint2v*)&b_lds[lrow + p * 32][lcol] = uw;
    }
    __syncthreads();
    bf16x8 af[2], bf[4];
#pragma unroll
    for (int t = 0; t < 2; ++t) af[t] = *(bf16x8*)&a_lds[wm + t * 16 + r][g * 8];
#pragma unroll
    for (int t = 0; t < 4; ++t) bf[t] = *(bf16x8*)&b_lds[t * 16 + r][g * 8];
#pragma unroll
    for (int mt = 0; mt < 2; ++mt)
#pragma unroll
      for (int nt = 0; nt < 4; ++nt)
        acc[mt][nt] = MFMA16(af[mt], bf[nt], acc[mt][nt]);
  }

#pragma unroll
  for (int mt = 0; mt < 2; ++mt)
#pragma unroll
    for (int nt = 0; nt < 4; ++nt) {
      const int e = nt * 16 + r;
#pragma unroll
      for (int j = 0; j < 4; ++j) {
        const int m = m0 + wm + mt * 16 + 4 * g + j;
        const int b = m >> 10, t = m & 1023;
        vsT[b * 65536 + e * 1024 + t] = __float2bfloat16(acc[mt][nt][j]);
      }
    }
}

// ---------------------------------------------------------------------------
// Kernel 3: fused attention, single-pass, register-resident exp(scores).
// grid = (S/64=16, H=16, B=8), 4 waves, each wave owns 16 query rows.
//   Swapped QK^T (mfma(K,Q)): lane (g,r) holds keys {16u+4g+j} of query r.
//   Main loop (unrolled 16x): 64 keys/iter -> 8 exps packed into 4 VGPRs,
//   f32 l accumulation on the side.
//   Post loop (unrolled 32x): per 32-key tile, NT-store attn = e*inv
//   (float4), LDS roundtrip e -> PV A-fragment, PV MFMA on unnormalized e.
//   PV output has query=ROW(4g+j): scale by invq[j]=__shfl(inv,4g+j).
// ---------------------------------------------------------------------------
__global__ __launch_bounds__(256, 2) void attn_kernel(
    const __hip_bfloat16* __restrict__ qs_, const __hip_bfloat16* __restrict__ ks_,
    const __hip_bfloat16* __restrict__ vsT_, float* __restrict__ attn_out,
    __hip_bfloat16* __restrict__ heads_)
{
  const int S = 1024, H = 16;
  const int tid = threadIdx.x, lane = tid & 63, wid = tid >> 6;
  const int g = lane >> 4, r = lane & 15;
  const int qb = blockIdx.x, h = blockIdx.y, b = blockIdx.z;
  const int bh = b * H + h;
  const int qrow = qb * 64 + wid * 16;
  __shared__ short p_lds[4][16][40];   // per-wave P staging (stride 80B)

  const short* qsp = (const short*)qs_;
  const short* ksp = (const short*)ks_;
  const short* vsp = (const short*)vsT_;
  short* headsp = (short*)heads_;

  const int qidx = (b * S + qrow + r) * 1024 + h * 64;
  const bf16x8 qf0 = *(const bf16x8*)&qsp[qidx + g * 8];
  const bf16x8 qf1 = *(const bf16x8*)&qsp[qidx + 32 + g * 8];
  const int kbase = (b * S + r) * 1024 + h * 64 + g * 8;

  // ---- single QK pass: e = exp(s) packed bf16 in registers, l in f32 ----
  unsigned int pk[128];              // 16-key group m -> pk[2m], pk[2m+1]
  float lsa0 = 0.f, lsa1 = 0.f, lsa2 = 0.f, lsa3 = 0.f;
#pragma unroll
  for (int i = 0; i < 16; ++i) {     // 64 keys per iteration
    const int t0 = i * 64;
    bf16x8 kf[8];
#pragma unroll
    for (int u = 0; u < 4; ++u) {
      kf[2 * u]     = *(const bf16x8*)&ksp[kbase + (t0 + 16 * u) * 1024];
      kf[2 * u + 1] = *(const bf16x8*)&ksp[kbase + (t0 + 16 * u) * 1024 + 32];
    }
    float es[4];
#pragma unroll
    for (int u = 0; u < 4; ++u) {
      f32x4 s = (f32x4){0.f, 0.f, 0.f, 0.f};
      s = MFMA16(kf[2 * u], qf0, s);
      s = MFMA16(kf[2 * u + 1], qf1, s);
      const float e0 = __expf(s[0]), e1 = __expf(s[1]);
      const float e2 = __expf(s[2]), e3 = __expf(s[3]);
      pk[i * 8 + 2 * u]     = pack2bf(e0, e1);
      pk[i * 8 + 2 * u + 1] = pack2bf(e2, e3);
      es[u] = (e0 + e1) + (e2 + e3);
    }
    lsa0 += es[0]; lsa1 += es[1]; lsa2 += es[2]; lsa3 += es[3];
  }
  float ls = (lsa0 + lsa1) + (lsa2 + lsa3);
  ls += __shfl_xor(ls, 16);
  ls += __shfl_xor(ls, 32);
  const float inv = 1.f / ls;        // normalizer for query r (lane's column)
  // normalizers for the PV output rows (queries 4g+j): lane 4g+j has r==4g+j
  float invq[4];
#pragma unroll
  for (int j = 0; j < 4; ++j) invq[j] = __shfl(inv, 4 * g + j);

  // ---- post loop: attn NT-stores + PV ----
  f32x4 hacc[4];
#pragma unroll
  for (int i = 0; i < 4; ++i) hacc[i] = (f32x4){0.f, 0.f, 0.f, 0.f};

  const int arow = ((b * S + qrow + r) * H + h) * S;   // attn row for query r
  const int vbase = b * 65536 + r * 1024 + g * 8;

#pragma unroll
  for (int j = 0; j < 32; ++j) {     // 32-key tiles
    const int tc = j * 32;
    bf16x8 vf[4];
#pragma unroll
    for (int nt = 0; nt < 4; ++nt)
      vf[nt] = *(const bf16x8*)&vsp[vbase + nt * 16384 + tc];
    // stage e (unnormalized) for the PV A-fragment
    uint2v w0 = {pk[4 * j + 0], pk[4 * j + 1]};   // keys tc+4g..tc+4g+3
    uint2v w1 = {pk[4 * j + 2], pk[4 * j + 3]};   // keys tc+16+4g..
    *(uint2v*)&p_lds[wid][r][0 * 16 + 4 * g] = w0;
    *(uint2v*)&p_lds[wid][r][1 * 16 + 4 * g] = w1;
    // attn stores (independent of the LDS path); lane's own inv (query r)
    f32x4 p0, p1;
    p0[0] = bflo(pk[4 * j + 0]) * inv; p0[1] = bfhi(pk[4 * j + 0]) * inv;
    p0[2] = bflo(pk[4 * j + 1]) * inv; p0[3] = bfhi(pk[4 * j + 1]) * inv;
    p1[0] = bflo(pk[4 * j + 2]) * inv; p1[1] = bfhi(pk[4 * j + 2]) * inv;
    p1[2] = bflo(pk[4 * j + 3]) * inv; p1[3] = bfhi(pk[4 * j + 3]) * inv;
    __builtin_nontemporal_store(p0, (f32x4*)&attn_out[arow + tc + 4 * g]);
    __builtin_nontemporal_store(p1, (f32x4*)&attn_out[arow + tc + 16 + 4 * g]);
    // cross-lane LDS hazard (within wave): drain DS queue before reading back
    asm volatile("s_waitcnt lgkmcnt(0)" ::: "memory");
    const bf16x8 pa = *(bf16x8*)&p_lds[wid][r][g * 8];
#pragma unroll
    for (int nt = 0; nt < 4; ++nt)
      hacc[nt] = MFMA16(pa, vf[nt], hacc[nt]);
  }

#pragma unroll
  for (int nt = 0; nt < 4; ++nt)
#pragma unroll
    for (int j = 0; j < 4; ++j)
      headsp[(bh * S + qrow + 4 * g + j) * 64 + nt * 16 + r] =
          f2bf(hacc[nt][j] * invq[j]);
}

// ---------------------------------------------------------------------------
// Kernel 4: outputs = mean_h(heads) @ Wo^T.  grid = 512, 16 rows per block.
// ---------------------------------------------------------------------------
__global__ __launch_bounds__(256) void out_kernel(
    const __hip_bfloat16* __restrict__ heads_, const float* __restrict__ Wo,
    float* __restrict__ out)
{
  __shared__ float hm[16][64];
  const int tid = threadIdx.x;
  const int m0 = blockIdx.x * 16;
  const short* headsp = (const short*)heads_;

  {
    const int row = tid >> 4, e4 = (tid & 15) * 4;
    const int m = m0 + row, b = m >> 10, s = m & 1023;
    float a0 = 0.f, a1 = 0.f, a2 = 0.f, a3 = 0.f;
    for (int hh = 0; hh < 16; ++hh) {
      typedef __attribute__((ext_vector_type(4))) short short4v;
      const short4v hv =
          *(const short4v*)&headsp[((b * 16 + hh) * 1024 + s) * 64 + e4];
      a0 += bf2f(hv[0]); a1 += bf2f(hv[1]); a2 += bf2f(hv[2]); a3 += bf2f(hv[3]);
    }
    const float sc = 1.f / 16.f;
    hm[row][e4 + 0] = a0 * sc; hm[row][e4 + 1] = a1 * sc;
    hm[row][e4 + 2] = a2 * sc; hm[row][e4 + 3] = a3 * sc;
  }
  __syncthreads();

  for (int c = 0; c < 4; ++c) {
    const int d = c * 256 + tid;
    float4 wo4[16];
#pragma unroll
    for (int i = 0; i < 16; ++i) wo4[i] = *(const float4*)&Wo[d * 64 + i * 4];
    for (int row = 0; row < 16; ++row) {
      float a = 0.f;
#pragma unroll
      for (int i = 0; i < 16; ++i) {
        const float4 h4 = *(const float4*)&hm[row][i * 4];
        a += h4.x * wo4[i].x + h4.y * wo4[i].y + h4.z * wo4[i].z + h4.w * wo4[i].w;
      }
      out[(m0 + row) * 1024 + d] = a;
    }
  }
}

// ---------------------------------------------------------------------------
extern "C" void kernel_launch(void* const* d_in, const int* in_sizes, int n_in,
                              void* d_out, int out_size, void* d_ws, size_t ws_size,
                              hipStream_t stream) {
  const float* q  = (const float*)d_in[0];
  const float* k  = (const float*)d_in[1];
  const float* v  = (const float*)d_in[2];
  const float* Wq = (const float*)d_in[3];
  const float* Wk = (const float*)d_in[4];
  const float* Wv = (const float*)d_in[5];
  const float* Wo = (const float*)d_in[6];

  float* out0 = (float*)d_out;                       // [8,1024,1024]
  float* attn = out0 + (size_t)8 * 1024 * 1024;      // [8,1024,16,1024]

  char* ws = (char*)d_ws;                            // 49 MB used
  __hip_bfloat16* qs    = (__hip_bfloat16*)(ws);                     // 16 MB
  __hip_bfloat16* ksbuf = (__hip_bfloat16*)(ws + (16u << 20));       // 16 MB
  __hip_bfloat16* vsT   = (__hip_bfloat16*)(ws + (32u << 20));       //  1 MB
  __hip_bfloat16* heads = (__hip_bfloat16*)(ws + (33u << 20));       // 16 MB

  dim3 blk(256);
  proj_qk_kernel<<<dim3(64, 16), blk, 0, stream>>>(q, k, Wq, Wk, qs, ksbuf);
  proj_v_kernel<<<dim3(64), blk, 0, stream>>>(v, Wv, vsT);
  attn_kernel<<<dim3(16, 16, 8), blk, 0, stream>>>(qs, ksbuf, vsT, attn, heads);
  out_kernel<<<dim3(512), blk, 0, stream>>>(heads, Wo, out0);
}

// Round 6
// 436.954 us; speedup vs baseline: 1.2832x; 1.2832x over previous
//
#include <hip/hip_runtime.h>
#include <hip/hip_bf16.h>

// ---------------------------------------------------------------------------
// InterpretableMultiHeadAttention  (B=8, S=1024, D=1024, H=16, dk=64)
//   outputs [B,S,D] fp32 ; attn [B,Sq,H,Sk] fp32  (concatenated in d_out)
// Pipeline:
//   1) proj_qk : qs = (q @ Wq^T)/8, ks = k @ Wk^T   (bf16, [b,s,(h,e)] layout)
//   2) proj_v  : vsT = (v @ Wv^T)^T                 (bf16, [b][e][t] layout)
//   3) attn    : single-pass, 16-wave blocks; wave (qg,kc) owns 16 queries x
//                256 keys -> e register-resident in pk[32] (NO spill; R5's
//                pk[128] spilled ~700 MB scratch).  Cross-wave l-reduce via
//                LDS; attn NT-stores + PV partials per key-chunk; 4-phase
//                LDS reduce of head partials, kc==3 fuses scale+store.
//   4) out     : outputs = mean_h(heads) @ Wo^T     (VALU)
// All f32->bf16 conversions are round-to-nearest-even.
// ---------------------------------------------------------------------------

typedef __attribute__((ext_vector_type(4))) float f32x4;
typedef __attribute__((ext_vector_type(8))) short bf16x8;
typedef __attribute__((ext_vector_type(2))) unsigned int uint2v;

#define MFMA16(a, b, c) __builtin_amdgcn_mfma_f32_16x16x32_bf16((a), (b), (c), 0, 0, 0)

__device__ __forceinline__ unsigned int rne16(float f) {
  unsigned int u = __float_as_uint(f);
  return u + 0x7fffu + ((u >> 16) & 1u);   // round-to-nearest-even in bit 16
}
__device__ __forceinline__ unsigned int pack2bf(float a, float b) {
  return (rne16(a) >> 16) | (rne16(b) & 0xffff0000u);
}
__device__ __forceinline__ short f2bf(float f) {
  return (short)(rne16(f) >> 16);
}
__device__ __forceinline__ float bf2f(short s) {
  return __uint_as_float(((unsigned int)(unsigned short)s) << 16);
}
__device__ __forceinline__ float bflo(unsigned int u) {
  return __uint_as_float(u << 16);
}
__device__ __forceinline__ float bfhi(unsigned int u) {
  return __uint_as_float(u & 0xffff0000u);
}

// ---------------------------------------------------------------------------
// Kernel 1: fused Q/K projection.  A [8192,1024] f32, W [1024,1024] f32 (B^T
// layout, i.e. [out,in]), C [8192,1024] bf16.  grid = (64, 16): y<8 -> Q, else K.
// ---------------------------------------------------------------------------
__global__ __launch_bounds__(256) void proj_qk_kernel(
    const float* __restrict__ qin, const float* __restrict__ kin,
    const float* __restrict__ Wq, const float* __restrict__ Wk,
    __hip_bfloat16* __restrict__ qs, __hip_bfloat16* __restrict__ ks)
{
  const int K = 1024, N = 1024;
  __shared__ short a_lds[128][40];   // padded stride 40 (80B) -> ~2-way banks
  __shared__ short b_lds[128][40];
  const int tid  = threadIdx.x;
  const int lane = tid & 63, wid = tid >> 6;
  const int g = lane >> 4, r = lane & 15;
  const bool isK = blockIdx.y >= 8;
  const float* A = isK ? kin : qin;
  const float* W = isK ? Wk : Wq;
  __hip_bfloat16* C = isK ? ks : qs;
  const float scale = isK ? 1.0f : 0.125f;   // 1/sqrt(dk)=1/8 folded into qs
  const int m0 = blockIdx.x * 128;
  const int n0 = (blockIdx.y & 7) * 128;
  const int wm = (wid >> 1) * 64, wn = (wid & 1) * 64;
  const int lrow = tid >> 3, lcol = (tid & 7) * 4;

  f32x4 acc[4][4];
#pragma unroll
  for (int i = 0; i < 4; ++i)
#pragma unroll
    for (int j = 0; j < 4; ++j) acc[i][j] = (f32x4){0.f, 0.f, 0.f, 0.f};

  for (int k0 = 0; k0 < K; k0 += 32) {
    float4 av[4], wv[4];
#pragma unroll
    for (int p = 0; p < 4; ++p) {
      av[p] = *(const float4*)&A[(m0 + lrow + p * 32) * K + k0 + lcol];
      wv[p] = *(const float4*)&W[(n0 + lrow + p * 32) * K + k0 + lcol];
    }
    __syncthreads();
#pragma unroll
    for (int p = 0; p < 4; ++p) {
      uint2v ua = {pack2bf(av[p].x, av[p].y), pack2bf(av[p].z, av[p].w)};
      uint2v uw = {pack2bf(wv[p].x, wv[p].y), pack2bf(wv[p].z, wv[p].w)};
      *(uint2v*)&a_lds[lrow + p * 32][lcol] = ua;
      *(uint2v*)&b_lds[lrow + p * 32][lcol] = uw;
    }
    __syncthreads();
    bf16x8 af[4], bf[4];
#pragma unroll
    for (int t = 0; t < 4; ++t) {
      af[t] = *(bf16x8*)&a_lds[wm + t * 16 + r][g * 8];
      bf[t] = *(bf16x8*)&b_lds[wn + t * 16 + r][g * 8];
    }
#pragma unroll
    for (int mt = 0; mt < 4; ++mt)
#pragma unroll
      for (int nt = 0; nt < 4; ++nt)
        acc[mt][nt] = MFMA16(af[mt], bf[nt], acc[mt][nt]);
  }

#pragma unroll
  for (int mt = 0; mt < 4; ++mt)
#pragma unroll
    for (int nt = 0; nt < 4; ++nt) {
      const int n = n0 + wn + nt * 16 + r;
#pragma unroll
      for (int j = 0; j < 4; ++j) {
        const int m = m0 + wm + mt * 16 + 4 * g + j;
        C[m * N + n] = __float2bfloat16(acc[mt][nt][j] * scale);
      }
    }
}

// ---------------------------------------------------------------------------
// Kernel 2: V projection, output TRANSPOSED per batch: vsT[b][e][t] bf16.
// M=8192 (b,t), N=64, K=1024.  grid = 64.
// ---------------------------------------------------------------------------
__global__ __launch_bounds__(256) void proj_v_kernel(
    const float* __restrict__ vin, const float* __restrict__ Wv,
    __hip_bfloat16* __restrict__ vsT)
{
  const int K = 1024;
  __shared__ short a_lds[128][40];
  __shared__ short b_lds[64][40];
  const int tid  = threadIdx.x;
  const int lane = tid & 63, wid = tid >> 6;
  const int g = lane >> 4, r = lane & 15;
  const int m0 = blockIdx.x * 128;
  const int wm = wid * 32;
  const int lrow = tid >> 3, lcol = (tid & 7) * 4;

  f32x4 acc[2][4];
#pragma unroll
  for (int i = 0; i < 2; ++i)
#pragma unroll
    for (int j = 0; j < 4; ++j) acc[i][j] = (f32x4){0.f, 0.f, 0.f, 0.f};

  for (int k0 = 0; k0 < K; k0 += 32) {
    float4 av[4], wv2[2];
#pragma unroll
    for (int p = 0; p < 4; ++p)
      av[p] = *(const float4*)&vin[(m0 + lrow + p * 32) * K + k0 + lcol];
#pragma unroll
    for (int p = 0; p < 2; ++p)
      wv2[p] = *(const float4*)&Wv[(lrow + p * 32) * K + k0 + lcol];
    __syncthreads();
#pragma unroll
    for (int p = 0; p < 4; ++p) {
      uint2v ua = {pack2bf(av[p].x, av[p].y), pack2bf(av[p].z, av[p].w)};
      *(uint2v*)&a_lds[lrow + p * 32][lcol] = ua;
    }
#pragma unroll
    for (int p = 0; p < 2; ++p) {
      uint2v uw = {pack2bf(wv2[p].x, wv2[p].y), pack2bf(wv2[p].z, wv2[p].w)};
      *(uint2v*)&b_lds[lrow + p * 32][lcol] = uw;
    }
    __syncthreads();
    bf16x8 af[2], bf[4];
#pragma unroll
    for (int t = 0; t < 2; ++t) af[t] = *(bf16x8*)&a_lds[wm + t * 16 + r][g * 8];
#pragma unroll
    for (int t = 0; t < 4; ++t) bf[t] = *(bf16x8*)&b_lds[t * 16 + r][g * 8];
#pragma unroll
    for (int mt = 0; mt < 2; ++mt)
#pragma unroll
      for (int nt = 0; nt < 4; ++nt)
        acc[mt][nt] = MFMA16(af[mt], bf[nt], acc[mt][nt]);
  }

#pragma unroll
  for (int mt = 0; mt < 2; ++mt)
#pragma unroll
    for (int nt = 0; nt < 4; ++nt) {
      const int e = nt * 16 + r;
#pragma unroll
      for (int j = 0; j < 4; ++j) {
        const int m = m0 + wm + mt * 16 + 4 * g + j;
        const int b = m >> 10, t = m & 1023;
        vsT[b * 65536 + e * 1024 + t] = __float2bfloat16(acc[mt][nt][j]);
      }
    }
}

// ---------------------------------------------------------------------------
// Kernel 3: fused attention, single-pass, register-resident exp(scores),
// 16-wave cooperative blocks.  grid = (S/64=16, H=16, B=8), block = 1024.
//   Wave (qg = wid&3, kc = wid>>2): queries [qrow, qrow+16), keys
//   [kc*256, kc*256+256).  Swapped QK^T (mfma(K,Q)): lane (g,r) holds key
//   rows 4g+j of query column r.  e = exp(s) packed bf16 in pk[32] VGPRs.
//   l: 2 shuffles -> LDS 4-way cross-wave reduce (1 barrier).
//   Post: per 32-key tile: NT-store attn = e*inv (float4, query r's inv),
//   LDS roundtrip e -> PV A-frag, PV MFMA (unnormalized partial).
//   Heads: 4-phase LDS reduce over kc; kc==3 fuses +hacc, *invq[j]
//   (invq[j]=__shfl(inv,4g+j) -- PV output query = ROW 4g+j), global store.
// ---------------------------------------------------------------------------
__global__ __launch_bounds__(1024, 4) void attn_kernel(
    const __hip_bfloat16* __restrict__ qs_, const __hip_bfloat16* __restrict__ ks_,
    const __hip_bfloat16* __restrict__ vsT_, float* __restrict__ attn_out,
    __hip_bfloat16* __restrict__ heads_)
{
  const int S = 1024, H = 16;
  const int tid = threadIdx.x, lane = tid & 63, wid = tid >> 6;
  const int g = lane >> 4, r = lane & 15;
  const int qg = wid & 3, kc = wid >> 2;
  const int qb = blockIdx.x, h = blockIdx.y, b = blockIdx.z;
  const int bh = b * H + h;
  const int qrow = qb * 64 + qg * 16;

  __shared__ short p_lds[16][16][40];    // per-wave P staging (stride 80B)
  __shared__ float heads_lds[64][80];    // stride 80 f32 -> 2-way banks (free)
  __shared__ float l_lds[4][4][16];      // [kc][qg][r]

  const short* qsp = (const short*)qs_;
  const short* ksp = (const short*)ks_;
  const short* vsp = (const short*)vsT_;
  short* headsp = (short*)heads_;

  const int qidx = (b * S + qrow + r) * 1024 + h * 64;
  const bf16x8 qf0 = *(const bf16x8*)&qsp[qidx + g * 8];
  const bf16x8 qf1 = *(const bf16x8*)&qsp[qidx + 32 + g * 8];
  const int kbase = (b * S + kc * 256 + r) * 1024 + h * 64 + g * 8;

  // ---- QK pass over this wave's 256 keys: e packed bf16 in 32 VGPRs ----
  unsigned int pk[32];
  float lsa0 = 0.f, lsa1 = 0.f, lsa2 = 0.f, lsa3 = 0.f;
#pragma unroll
  for (int i = 0; i < 4; ++i) {      // 64 keys per iteration
    const int t0 = i * 64;
    bf16x8 kf[8];
#pragma unroll
    for (int u = 0; u < 4; ++u) {
      kf[2 * u]     = *(const bf16x8*)&ksp[kbase + (t0 + 16 * u) * 1024];
      kf[2 * u + 1] = *(const bf16x8*)&ksp[kbase + (t0 + 16 * u) * 1024 + 32];
    }
    float es[4];
#pragma unroll
    for (int u = 0; u < 4; ++u) {
      f32x4 s = (f32x4){0.f, 0.f, 0.f, 0.f};
      s = MFMA16(kf[2 * u], qf0, s);
      s = MFMA16(kf[2 * u + 1], qf1, s);
      const float e0 = __expf(s[0]), e1 = __expf(s[1]);
      const float e2 = __expf(s[2]), e3 = __expf(s[3]);
      pk[i * 8 + 2 * u]     = pack2bf(e0, e1);
      pk[i * 8 + 2 * u + 1] = pack2bf(e2, e3);
      es[u] = (e0 + e1) + (e2 + e3);
    }
    lsa0 += es[0]; lsa1 += es[1]; lsa2 += es[2]; lsa3 += es[3];
  }
  float ls = (lsa0 + lsa1) + (lsa2 + lsa3);
  ls += __shfl_xor(ls, 16);
  ls += __shfl_xor(ls, 32);          // per-lane: sum over this wave's 256 keys
  if (g == 0) l_lds[kc][qg][r] = ls;
  __syncthreads();
  const float lf = (l_lds[0][qg][r] + l_lds[1][qg][r]) +
                   (l_lds[2][qg][r] + l_lds[3][qg][r]);
  const float inv = 1.f / lf;        // normalizer for query r (lane's column)
  float invq[4];
#pragma unroll
  for (int j = 0; j < 4; ++j) invq[j] = __shfl(inv, 4 * g + j);

  // ---- post loop: attn NT-stores + PV partials over this wave's chunk ----
  f32x4 hacc[4];
#pragma unroll
  for (int i = 0; i < 4; ++i) hacc[i] = (f32x4){0.f, 0.f, 0.f, 0.f};

  const int arow = ((b * S + qrow + r) * H + h) * S + kc * 256;
  const int vbase = b * 65536 + r * 1024 + g * 8 + kc * 256;

#pragma unroll
  for (int j = 0; j < 8; ++j) {      // 32-key tiles within the chunk
    const int tcl = j * 32;
    bf16x8 vf[4];
#pragma unroll
    for (int nt = 0; nt < 4; ++nt)
      vf[nt] = *(const bf16x8*)&vsp[vbase + nt * 16384 + tcl];
    // stage e (unnormalized) for the PV A-fragment
    uint2v w0 = {pk[4 * j + 0], pk[4 * j + 1]};   // keys tcl+4g..+3
    uint2v w1 = {pk[4 * j + 2], pk[4 * j + 3]};   // keys tcl+16+4g..+3
    *(uint2v*)&p_lds[wid][r][0 * 16 + 4 * g] = w0;
    *(uint2v*)&p_lds[wid][r][1 * 16 + 4 * g] = w1;
    // attn stores (lane's own inv, query r)
    f32x4 p0, p1;
    p0[0] = bflo(pk[4 * j + 0]) * inv; p0[1] = bfhi(pk[4 * j + 0]) * inv;
    p0[2] = bflo(pk[4 * j + 1]) * inv; p0[3] = bfhi(pk[4 * j + 1]) * inv;
    p1[0] = bflo(pk[4 * j + 2]) * inv; p1[1] = bfhi(pk[4 * j + 2]) * inv;
    p1[2] = bflo(pk[4 * j + 3]) * inv; p1[3] = bfhi(pk[4 * j + 3]) * inv;
    __builtin_nontemporal_store(p0, (f32x4*)&attn_out[arow + tcl + 4 * g]);
    __builtin_nontemporal_store(p1, (f32x4*)&attn_out[arow + tcl + 16 + 4 * g]);
    // cross-lane LDS hazard (within wave): drain DS queue before reading back
    asm volatile("s_waitcnt lgkmcnt(0)" ::: "memory");
    const bf16x8 pa = *(bf16x8*)&p_lds[wid][r][g * 8];
#pragma unroll
    for (int nt = 0; nt < 4; ++nt)
      hacc[nt] = MFMA16(pa, vf[nt], hacc[nt]);
  }

  // ---- heads: 4-phase cross-wave reduce over kc (disjoint rows per qg) ----
  const int hrow = qg * 16 + 4 * g;
#pragma unroll
  for (int kk = 0; kk < 3; ++kk) {
    if (kc == kk) {
#pragma unroll
      for (int nt = 0; nt < 4; ++nt)
#pragma unroll
        for (int j = 0; j < 4; ++j) {
          float* p = &heads_lds[hrow + j][nt * 16 + r];
          *p = (kk == 0) ? hacc[nt][j] : (*p + hacc[nt][j]);
        }
    }
    __syncthreads();
  }
  if (kc == 3) {
#pragma unroll
    for (int nt = 0; nt < 4; ++nt)
#pragma unroll
      for (int j = 0; j < 4; ++j) {
        const float hv = heads_lds[hrow + j][nt * 16 + r] + hacc[nt][j];
        headsp[(bh * S + qrow + 4 * g + j) * 64 + nt * 16 + r] =
            f2bf(hv * invq[j]);
      }
  }
}

// ---------------------------------------------------------------------------
// Kernel 4: outputs = mean_h(heads) @ Wo^T.  grid = 512, 16 rows per block.
// ---------------------------------------------------------------------------
__global__ __launch_bounds__(256) void out_kernel(
    const __hip_bfloat16* __restrict__ heads_, const float* __restrict__ Wo,
    float* __restrict__ out)
{
  __shared__ float hm[16][64];
  const int tid = threadIdx.x;
  const int m0 = blockIdx.x * 16;
  const short* headsp = (const short*)heads_;

  {
    const int row = tid >> 4, e4 = (tid & 15) * 4;
    const int m = m0 + row, b = m >> 10, s = m & 1023;
    float a0 = 0.f, a1 = 0.f, a2 = 0.f, a3 = 0.f;
    for (int hh = 0; hh < 16; ++hh) {
      typedef __attribute__((ext_vector_type(4))) short short4v;
      const short4v hv =
          *(const short4v*)&headsp[((b * 16 + hh) * 1024 + s) * 64 + e4];
      a0 += bf2f(hv[0]); a1 += bf2f(hv[1]); a2 += bf2f(hv[2]); a3 += bf2f(hv[3]);
    }
    const float sc = 1.f / 16.f;
    hm[row][e4 + 0] = a0 * sc; hm[row][e4 + 1] = a1 * sc;
    hm[row][e4 + 2] = a2 * sc; hm[row][e4 + 3] = a3 * sc;
  }
  __syncthreads();

  for (int c = 0; c < 4; ++c) {
    const int d = c * 256 + tid;
    float4 wo4[16];
#pragma unroll
    for (int i = 0; i < 16; ++i) wo4[i] = *(const float4*)&Wo[d * 64 + i * 4];
    for (int row = 0; row < 16; ++row) {
      float a = 0.f;
#pragma unroll
      for (int i = 0; i < 16; ++i) {
        const float4 h4 = *(const float4*)&hm[row][i * 4];
        a += h4.x * wo4[i].x + h4.y * wo4[i].y + h4.z * wo4[i].z + h4.w * wo4[i].w;
      }
      out[(m0 + row) * 1024 + d] = a;
    }
  }
}

// ---------------------------------------------------------------------------
extern "C" void kernel_launch(void* const* d_in, const int* in_sizes, int n_in,
                              void* d_out, int out_size, void* d_ws, size_t ws_size,
                              hipStream_t stream) {
  const float* q  = (const float*)d_in[0];
  const float* k  = (const float*)d_in[1];
  const float* v  = (const float*)d_in[2];
  const float* Wq = (const float*)d_in[3];
  const float* Wk = (const float*)d_in[4];
  const float* Wv = (const float*)d_in[5];
  const float* Wo = (const float*)d_in[6];

  float* out0 = (float*)d_out;                       // [8,1024,1024]
  float* attn = out0 + (size_t)8 * 1024 * 1024;      // [8,1024,16,1024]

  char* ws = (char*)d_ws;                            // 49 MB used
  __hip_bfloat16* qs    = (__hip_bfloat16*)(ws);                     // 16 MB
  __hip_bfloat16* ksbuf = (__hip_bfloat16*)(ws + (16u << 20));       // 16 MB
  __hip_bfloat16* vsT   = (__hip_bfloat16*)(ws + (32u << 20));       //  1 MB
  __hip_bfloat16* heads = (__hip_bfloat16*)(ws + (33u << 20));       // 16 MB

  proj_qk_kernel<<<dim3(64, 16), dim3(256), 0, stream>>>(q, k, Wq, Wk, qs, ksbuf);
  proj_v_kernel<<<dim3(64), dim3(256), 0, stream>>>(v, Wv, vsT);
  attn_kernel<<<dim3(16, 16, 8), dim3(1024), 0, stream>>>(qs, ksbuf, vsT, attn, heads);
  out_kernel<<<dim3(512), dim3(256), 0, stream>>>(heads, Wo, out0);
}

// Round 7
// 420.058 us; speedup vs baseline: 1.3348x; 1.0402x over previous
//
#include <hip/hip_runtime.h>
#include <hip/hip_bf16.h>

// ---------------------------------------------------------------------------
// InterpretableMultiHeadAttention  (B=8, S=1024, D=1024, H=16, dk=64)
//   outputs [B,S,D] fp32 ; attn [B,Sq,H,Sk] fp32  (concatenated in d_out)
// Pipeline:
//   1) proj_qk : qs = (q @ Wq^T)/8, ks = k @ Wk^T   (bf16, [b,s,(h,e)] layout)
//   2) proj_v  : vsT = (v @ Wv^T)^T                 (bf16, [b][e][t] layout)
//   3) attn    : single-pass, 4-wave (256-thr) blocks so 4 blocks/CU run
//                PHASE-SHIFTED (QK of one block overlaps PV of another);
//                wave kc owns 16 queries x 256 keys, e register-resident in
//                pk[32]; l via LDS cross-wave reduce; P staged to LDS once
//                (single lgkmcnt drain), merged {V-load, P-read, MFMA,
//                attn NT-store} loop; heads reduced via LDS overlay with
//                row-indexed normalizer.
//   4) out     : outputs = mean_h(heads) @ Wo^T     (VALU)
// All f32->bf16 conversions are round-to-nearest-even.
// ---------------------------------------------------------------------------

typedef __attribute__((ext_vector_type(4))) float f32x4;
typedef __attribute__((ext_vector_type(8))) short bf16x8;
typedef __attribute__((ext_vector_type(4))) short short4v;
typedef __attribute__((ext_vector_type(2))) unsigned int uint2v;

#define MFMA16(a, b, c) __builtin_amdgcn_mfma_f32_16x16x32_bf16((a), (b), (c), 0, 0, 0)

__device__ __forceinline__ unsigned int rne16(float f) {
  unsigned int u = __float_as_uint(f);
  return u + 0x7fffu + ((u >> 16) & 1u);   // round-to-nearest-even in bit 16
}
__device__ __forceinline__ unsigned int pack2bf(float a, float b) {
  return (rne16(a) >> 16) | (rne16(b) & 0xffff0000u);
}
__device__ __forceinline__ short f2bf(float f) {
  return (short)(rne16(f) >> 16);
}
__device__ __forceinline__ float bf2f(short s) {
  return __uint_as_float(((unsigned int)(unsigned short)s) << 16);
}
__device__ __forceinline__ float bflo(unsigned int u) {
  return __uint_as_float(u << 16);
}
__device__ __forceinline__ float bfhi(unsigned int u) {
  return __uint_as_float(u & 0xffff0000u);
}

// ---------------------------------------------------------------------------
// Kernel 1: fused Q/K projection.  A [8192,1024] f32, W [1024,1024] f32 (B^T
// layout, i.e. [out,in]), C [8192,1024] bf16.  grid = (64, 16): y<8 -> Q, else K.
// ---------------------------------------------------------------------------
__global__ __launch_bounds__(256) void proj_qk_kernel(
    const float* __restrict__ qin, const float* __restrict__ kin,
    const float* __restrict__ Wq, const float* __restrict__ Wk,
    __hip_bfloat16* __restrict__ qs, __hip_bfloat16* __restrict__ ks)
{
  const int K = 1024, N = 1024;
  __shared__ short a_lds[128][40];   // padded stride 40 (80B) -> ~2-way banks
  __shared__ short b_lds[128][40];
  const int tid  = threadIdx.x;
  const int lane = tid & 63, wid = tid >> 6;
  const int g = lane >> 4, r = lane & 15;
  const bool isK = blockIdx.y >= 8;
  const float* A = isK ? kin : qin;
  const float* W = isK ? Wk : Wq;
  __hip_bfloat16* C = isK ? ks : qs;
  const float scale = isK ? 1.0f : 0.125f;   // 1/sqrt(dk)=1/8 folded into qs
  const int m0 = blockIdx.x * 128;
  const int n0 = (blockIdx.y & 7) * 128;
  const int wm = (wid >> 1) * 64, wn = (wid & 1) * 64;
  const int lrow = tid >> 3, lcol = (tid & 7) * 4;

  f32x4 acc[4][4];
#pragma unroll
  for (int i = 0; i < 4; ++i)
#pragma unroll
    for (int j = 0; j < 4; ++j) acc[i][j] = (f32x4){0.f, 0.f, 0.f, 0.f};

  for (int k0 = 0; k0 < K; k0 += 32) {
    float4 av[4], wv[4];
#pragma unroll
    for (int p = 0; p < 4; ++p) {
      av[p] = *(const float4*)&A[(m0 + lrow + p * 32) * K + k0 + lcol];
      wv[p] = *(const float4*)&W[(n0 + lrow + p * 32) * K + k0 + lcol];
    }
    __syncthreads();
#pragma unroll
    for (int p = 0; p < 4; ++p) {
      uint2v ua = {pack2bf(av[p].x, av[p].y), pack2bf(av[p].z, av[p].w)};
      uint2v uw = {pack2bf(wv[p].x, wv[p].y), pack2bf(wv[p].z, wv[p].w)};
      *(uint2v*)&a_lds[lrow + p * 32][lcol] = ua;
      *(uint2v*)&b_lds[lrow + p * 32][lcol] = uw;
    }
    __syncthreads();
    bf16x8 af[4], bf[4];
#pragma unroll
    for (int t = 0; t < 4; ++t) {
      af[t] = *(bf16x8*)&a_lds[wm + t * 16 + r][g * 8];
      bf[t] = *(bf16x8*)&b_lds[wn + t * 16 + r][g * 8];
    }
#pragma unroll
    for (int mt = 0; mt < 4; ++mt)
#pragma unroll
      for (int nt = 0; nt < 4; ++nt)
        acc[mt][nt] = MFMA16(af[mt], bf[nt], acc[mt][nt]);
  }

#pragma unroll
  for (int mt = 0; mt < 4; ++mt)
#pragma unroll
    for (int nt = 0; nt < 4; ++nt) {
      const int n = n0 + wn + nt * 16 + r;
#pragma unroll
      for (int j = 0; j < 4; ++j) {
        const int m = m0 + wm + mt * 16 + 4 * g + j;
        C[m * N + n] = __float2bfloat16(acc[mt][nt][j] * scale);
      }
    }
}

// ---------------------------------------------------------------------------
// Kernel 2: V projection, output TRANSPOSED per batch: vsT[b][e][t] bf16.
// M=8192 (b,t), N=64, K=1024.  grid = 64.
// ---------------------------------------------------------------------------
__global__ __launch_bounds__(256) void proj_v_kernel(
    const float* __restrict__ vin, const float* __restrict__ Wv,
    __hip_bfloat16* __restrict__ vsT)
{
  const int K = 1024;
  __shared__ short a_lds[128][40];
  __shared__ short b_lds[64][40];
  const int tid  = threadIdx.x;
  const int lane = tid & 63, wid = tid >> 6;
  const int g = lane >> 4, r = lane & 15;
  const int m0 = blockIdx.x * 128;
  const int wm = wid * 32;
  const int lrow = tid >> 3, lcol = (tid & 7) * 4;

  f32x4 acc[2][4];
#pragma unroll
  for (int i = 0; i < 2; ++i)
#pragma unroll
    for (int j = 0; j < 4; ++j) acc[i][j] = (f32x4){0.f, 0.f, 0.f, 0.f};

  for (int k0 = 0; k0 < K; k0 += 32) {
    float4 av[4], wv2[2];
#pragma unroll
    for (int p = 0; p < 4; ++p)
      av[p] = *(const float4*)&vin[(m0 + lrow + p * 32) * K + k0 + lcol];
#pragma unroll
    for (int p = 0; p < 2; ++p)
      wv2[p] = *(const float4*)&Wv[(lrow + p * 32) * K + k0 + lcol];
    __syncthreads();
#pragma unroll
    for (int p = 0; p < 4; ++p) {
      uint2v ua = {pack2bf(av[p].x, av[p].y), pack2bf(av[p].z, av[p].w)};
      *(uint2v*)&a_lds[lrow + p * 32][lcol] = ua;
    }
#pragma unroll
    for (int p = 0; p < 2; ++p) {
      uint2v uw = {pack2bf(wv2[p].x, wv2[p].y), pack2bf(wv2[p].z, wv2[p].w)};
      *(uint2v*)&b_lds[lrow + p * 32][lcol] = uw;
    }
    __syncthreads();
    bf16x8 af[2], bf[4];
#pragma unroll
    for (int t = 0; t < 2; ++t) af[t] = *(bf16x8*)&a_lds[wm + t * 16 + r][g * 8];
#pragma unroll
    for (int t = 0; t < 4; ++t) bf[t] = *(bf16x8*)&b_lds[t * 16 + r][g * 8];
#pragma unroll
    for (int mt = 0; mt < 2; ++mt)
#pragma unroll
      for (int nt = 0; nt < 4; ++nt)
        acc[mt][nt] = MFMA16(af[mt], bf[nt], acc[mt][nt]);
  }

#pragma unroll
  for (int mt = 0; mt < 2; ++mt)
#pragma unroll
    for (int nt = 0; nt < 4; ++nt) {
      const int e = nt * 16 + r;
#pragma unroll
      for (int j = 0; j < 4; ++j) {
        const int m = m0 + wm + mt * 16 + 4 * g + j;
        const int b = m >> 10, t = m & 1023;
        vsT[b * 65536 + e * 1024 + t] = __float2bfloat16(acc[mt][nt][j]);
      }
    }
}

// ---------------------------------------------------------------------------
// Kernel 3: fused attention.  grid = (S/16=64, H=16, B=8), block = 256 (4
// waves).  Wave kc owns queries [qrow,qrow+16) x keys [kc*256, kc*256+256).
//   Swapped QK^T (mfma(K,Q)): lane (g,r) holds key rows 4g+j of query col r.
//   e = exp(s) packed bf16 in pk[32] VGPRs.  l: 2 shuffles + LDS 4-way
//   cross-wave reduce (1 barrier).  P staged to per-wave LDS [16][260] in one
//   burst (single lgkmcnt drain).  Merged loop: {4 V loads, 1 b128 P read,
//   4 PV MFMA, pk-unpack, 2 NT attn stores}.  Heads: partials into an LDS
//   OVERLAY of the P region (barrier first), then thread-distributed final
//   sum scaled by row-indexed inv (no invq shuffles).
// ---------------------------------------------------------------------------
__global__ __launch_bounds__(256, 4) void attn_kernel(
    const __hip_bfloat16* __restrict__ qs_, const __hip_bfloat16* __restrict__ ks_,
    const __hip_bfloat16* __restrict__ vsT_, float* __restrict__ attn_out,
    __hip_bfloat16* __restrict__ heads_)
{
  const int S = 1024, H = 16;
  const int tid = threadIdx.x, lane = tid & 63, kc = tid >> 6;
  const int g = lane >> 4, r = lane & 15;
  const int h = blockIdx.y, b = blockIdx.z;
  const int bh = b * H + h;
  const int qrow = blockIdx.x * 16;

  __shared__ short p_big[4][16][260];    // per-wave P (stride 520B: ~2-4 way)
  __shared__ float l_lds[4][16];         // [kc][r]
  float (*heads_ov)[16][80] = (float (*)[16][80])p_big;  // overlay after PV

  const short* qsp = (const short*)qs_;
  const short* ksp = (const short*)ks_;
  const short* vsp = (const short*)vsT_;
  short* headsp = (short*)heads_;

  const int qidx = (b * S + qrow + r) * 1024 + h * 64;
  const bf16x8 qf0 = *(const bf16x8*)&qsp[qidx + g * 8];
  const bf16x8 qf1 = *(const bf16x8*)&qsp[qidx + 32 + g * 8];
  const int kbase = (b * S + kc * 256 + r) * 1024 + h * 64 + g * 8;

  // ---- QK pass over this wave's 256 keys: e packed bf16 in 32 VGPRs ----
  unsigned int pk[32];
  float lsa0 = 0.f, lsa1 = 0.f, lsa2 = 0.f, lsa3 = 0.f;
#pragma unroll
  for (int i = 0; i < 4; ++i) {      // 64 keys per iteration
    const int t0 = i * 64;
    bf16x8 kf[8];
#pragma unroll
    for (int u = 0; u < 4; ++u) {
      kf[2 * u]     = *(const bf16x8*)&ksp[kbase + (t0 + 16 * u) * 1024];
      kf[2 * u + 1] = *(const bf16x8*)&ksp[kbase + (t0 + 16 * u) * 1024 + 32];
    }
    float es[4];
#pragma unroll
    for (int u = 0; u < 4; ++u) {
      f32x4 s = (f32x4){0.f, 0.f, 0.f, 0.f};
      s = MFMA16(kf[2 * u], qf0, s);
      s = MFMA16(kf[2 * u + 1], qf1, s);
      const float e0 = __expf(s[0]), e1 = __expf(s[1]);
      const float e2 = __expf(s[2]), e3 = __expf(s[3]);
      pk[i * 8 + 2 * u]     = pack2bf(e0, e1);
      pk[i * 8 + 2 * u + 1] = pack2bf(e2, e3);
      es[u] = (e0 + e1) + (e2 + e3);
    }
    lsa0 += es[0]; lsa1 += es[1]; lsa2 += es[2]; lsa3 += es[3];
  }
  float ls = (lsa0 + lsa1) + (lsa2 + lsa3);
  ls += __shfl_xor(ls, 16);
  ls += __shfl_xor(ls, 32);          // per-lane: sum over this wave's 256 keys
  if (g == 0) l_lds[kc][r] = ls;
  __syncthreads();
  const float lf = (l_lds[0][r] + l_lds[1][r]) + (l_lds[2][r] + l_lds[3][r]);
  const float inv = 1.f / lf;        // normalizer for query r (lane's column)

  // ---- stage ALL P to LDS in one burst, single drain ----
#pragma unroll
  for (int j = 0; j < 8; ++j) {
    uint2v w0 = {pk[4 * j + 0], pk[4 * j + 1]};   // keys j*32+4g..+3
    uint2v w1 = {pk[4 * j + 2], pk[4 * j + 3]};   // keys j*32+16+4g..+3
    *(uint2v*)&p_big[kc][r][j * 32 + 4 * g] = w0;
    *(uint2v*)&p_big[kc][r][j * 32 + 16 + 4 * g] = w1;
  }
  // cross-lane (within-wave) LDS hazard: drain DS queue once
  asm volatile("s_waitcnt lgkmcnt(0)" ::: "memory");

  // ---- merged loop: PV MFMA + attn NT stores ----
  f32x4 hacc[4];
#pragma unroll
  for (int i = 0; i < 4; ++i) hacc[i] = (f32x4){0.f, 0.f, 0.f, 0.f};

  const int arow = ((b * S + qrow + r) * H + h) * S + kc * 256;
  const int vbase = b * 65536 + r * 1024 + g * 8 + kc * 256;

#pragma unroll
  for (int j = 0; j < 8; ++j) {      // 32-key tiles within the chunk
    const int tcl = j * 32;
    bf16x8 vf[4];
#pragma unroll
    for (int nt = 0; nt < 4; ++nt)
      vf[nt] = *(const bf16x8*)&vsp[vbase + nt * 16384 + tcl];
    const bf16x8 pa = *(bf16x8*)&p_big[kc][r][tcl + g * 8];
#pragma unroll
    for (int nt = 0; nt < 4; ++nt)
      hacc[nt] = MFMA16(pa, vf[nt], hacc[nt]);
    // attn stores (lane's own inv, query r)
    f32x4 p0, p1;
    p0[0] = bflo(pk[4 * j + 0]) * inv; p0[1] = bfhi(pk[4 * j + 0]) * inv;
    p0[2] = bflo(pk[4 * j + 1]) * inv; p0[3] = bfhi(pk[4 * j + 1]) * inv;
    p1[0] = bflo(pk[4 * j + 2]) * inv; p1[1] = bfhi(pk[4 * j + 2]) * inv;
    p1[2] = bflo(pk[4 * j + 3]) * inv; p1[3] = bfhi(pk[4 * j + 3]) * inv;
    __builtin_nontemporal_store(p0, (f32x4*)&attn_out[arow + tcl + 4 * g]);
    __builtin_nontemporal_store(p1, (f32x4*)&attn_out[arow + tcl + 16 + 4 * g]);
  }
  __syncthreads();                   // p_big dead -> safe to overlay

  // ---- heads partials into overlay; PV output query = ROW 4g+j ----
#pragma unroll
  for (int nt = 0; nt < 4; ++nt)
#pragma unroll
    for (int j = 0; j < 4; ++j)
      heads_ov[kc][4 * g + j][nt * 16 + r] = hacc[nt][j];
  __syncthreads();

  // ---- final: distributed 4-way sum, row-indexed normalizer, store ----
  {
    const int row = tid >> 4, c4 = (tid & 15) * 4;
    const float lrow = (l_lds[0][row] + l_lds[1][row]) +
                       (l_lds[2][row] + l_lds[3][row]);
    const float invr = 1.f / lrow;
    short4v hv;
#pragma unroll
    for (int i = 0; i < 4; ++i) {
      const float s4 = (heads_ov[0][row][c4 + i] + heads_ov[1][row][c4 + i]) +
                       (heads_ov[2][row][c4 + i] + heads_ov[3][row][c4 + i]);
      hv[i] = f2bf(s4 * invr);
    }
    *(short4v*)&headsp[(bh * S + qrow + row) * 64 + c4] = hv;
  }
}

// ---------------------------------------------------------------------------
// Kernel 4: outputs = mean_h(heads) @ Wo^T.  grid = 512, 16 rows per block.
// ---------------------------------------------------------------------------
__global__ __launch_bounds__(256) void out_kernel(
    const __hip_bfloat16* __restrict__ heads_, const float* __restrict__ Wo,
    float* __restrict__ out)
{
  __shared__ float hm[16][64];
  const int tid = threadIdx.x;
  const int m0 = blockIdx.x * 16;
  const short* headsp = (const short*)heads_;

  {
    const int row = tid >> 4, e4 = (tid & 15) * 4;
    const int m = m0 + row, b = m >> 10, s = m & 1023;
    float a0 = 0.f, a1 = 0.f, a2 = 0.f, a3 = 0.f;
    for (int hh = 0; hh < 16; ++hh) {
      const short4v hv =
          *(const short4v*)&headsp[((b * 16 + hh) * 1024 + s) * 64 + e4];
      a0 += bf2f(hv[0]); a1 += bf2f(hv[1]); a2 += bf2f(hv[2]); a3 += bf2f(hv[3]);
    }
    const float sc = 1.f / 16.f;
    hm[row][e4 + 0] = a0 * sc; hm[row][e4 + 1] = a1 * sc;
    hm[row][e4 + 2] = a2 * sc; hm[row][e4 + 3] = a3 * sc;
  }
  __syncthreads();

  for (int c = 0; c < 4; ++c) {
    const int d = c * 256 + tid;
    float4 wo4[16];
#pragma unroll
    for (int i = 0; i < 16; ++i) wo4[i] = *(const float4*)&Wo[d * 64 + i * 4];
    for (int row = 0; row < 16; ++row) {
      float a = 0.f;
#pragma unroll
      for (int i = 0; i < 16; ++i) {
        const float4 h4 = *(const float4*)&hm[row][i * 4];
        a += h4.x * wo4[i].x + h4.y * wo4[i].y + h4.z * wo4[i].z + h4.w * wo4[i].w;
      }
      out[(m0 + row) * 1024 + d] = a;
    }
  }
}

// ---------------------------------------------------------------------------
extern "C" void kernel_launch(void* const* d_in, const int* in_sizes, int n_in,
                              void* d_out, int out_size, void* d_ws, size_t ws_size,
                              hipStream_t stream) {
  const float* q  = (const float*)d_in[0];
  const float* k  = (const float*)d_in[1];
  const float* v  = (const float*)d_in[2];
  const float* Wq = (const float*)d_in[3];
  const float* Wk = (const float*)d_in[4];
  const float* Wv = (const float*)d_in[5];
  const float* Wo = (const float*)d_in[6];

  float* out0 = (float*)d_out;                       // [8,1024,1024]
  float* attn = out0 + (size_t)8 * 1024 * 1024;      // [8,1024,16,1024]

  char* ws = (char*)d_ws;                            // 49 MB used
  __hip_bfloat16* qs    = (__hip_bfloat16*)(ws);                     // 16 MB
  __hip_bfloat16* ksbuf = (__hip_bfloat16*)(ws + (16u << 20));       // 16 MB
  __hip_bfloat16* vsT   = (__hip_bfloat16*)(ws + (32u << 20));       //  1 MB
  __hip_bfloat16* heads = (__hip_bfloat16*)(ws + (33u << 20));       // 16 MB

  proj_qk_kernel<<<dim3(64, 16), dim3(256), 0, stream>>>(q, k, Wq, Wk, qs, ksbuf);
  proj_v_kernel<<<dim3(64), dim3(256), 0, stream>>>(v, Wv, vsT);
  attn_kernel<<<dim3(64, 16, 8), dim3(256), 0, stream>>>(qs, ksbuf, vsT, attn, heads);
  out_kernel<<<dim3(512), dim3(256), 0, stream>>>(heads, Wo, out0);
}